// Round 7
// baseline (186.793 us; speedup 1.0000x reference)
//
#include <hip/hip_runtime.h>

typedef __bf16 bf16x8 __attribute__((ext_vector_type(8)));
typedef __bf16 bf16x4 __attribute__((ext_vector_type(4)));
typedef float f32x4 __attribute__((ext_vector_type(4)));

#define MFMA16(a,b,c) __builtin_amdgcn_mfma_f32_16x16x32_bf16((a),(b),(c),0,0,0)

__device__ __forceinline__ void gload_lds16(const void* g, void* l) {
    __builtin_amdgcn_global_load_lds(
        (const __attribute__((address_space(1))) void*)g,
        (__attribute__((address_space(3))) void*)l, 16, 0, 0);
}

// Problem constants: B=8 S=1024 IN=512 ORIG=64 E=512 H=8 hd=64
// xc: [8192][576]  Wqkv: [1536][576]  Wo: [512][512]
// q_ws/k_ws: [64(bh)][1024(s)][64(d)] bf16 ; vt_ws: [64(bh)][64(d)][1024(s)] bf16

__global__ __launch_bounds__(256) void k_convert(
    const float* __restrict__ x, const float* __restrict__ inp,
    const float* __restrict__ Wqkv, const float* __restrict__ Wo,
    __bf16* __restrict__ xc, __bf16* __restrict__ wq, __bf16* __restrict__ wo)
{
    const unsigned C1 = 589824u;   // 8192*576/8
    const unsigned C2 = 110592u;   // 1536*576/8
    unsigned i = blockIdx.x * 256u + threadIdx.x;   // 8-element chunk index
    if (i < C1) {
        unsigned e = i * 8u;
        unsigned m = e / 576u, k = e - m * 576u;
        const float* p = (k < 512u) ? x + (size_t)m * 512u + k
                                    : inp + (size_t)m * 64u + (k - 512u);
        f32x4 a = *(const f32x4*)p, b = *(const f32x4*)(p + 4);
        bf16x8 o;
#pragma unroll
        for (int j = 0; j < 4; ++j) { o[j] = (__bf16)a[j]; o[j + 4] = (__bf16)b[j]; }
        *(bf16x8*)&xc[e] = o;
    } else if (i < C1 + C2) {
        unsigned e = (i - C1) * 8u;
        f32x4 a = *(const f32x4*)&Wqkv[e], b = *(const f32x4*)&Wqkv[e + 4];
        bf16x8 o;
#pragma unroll
        for (int j = 0; j < 4; ++j) { o[j] = (__bf16)a[j]; o[j + 4] = (__bf16)b[j]; }
        *(bf16x8*)&wq[e] = o;
    } else {
        unsigned e = (i - C1 - C2) * 8u;
        f32x4 a = *(const f32x4*)&Wo[e], b = *(const f32x4*)&Wo[e + 4];
        bf16x8 o;
#pragma unroll
        for (int j = 0; j < 4; ++j) { o[j] = (__bf16)a[j]; o[j + 4] = (__bf16)b[j]; }
        *(bf16x8*)&wo[e] = o;
    }
}

// ---------------- QKV GEMM (m97 structure): 128x128 tile, BK=32, global_load_lds ----------------
__global__ __launch_bounds__(256) void k_qkv_gemm(
    const __bf16* __restrict__ A, const __bf16* __restrict__ W,
    const float* __restrict__ bias,
    __bf16* __restrict__ q_ws, __bf16* __restrict__ k_ws, __bf16* __restrict__ vt_ws)
{
    const int K = 576;
    __shared__ __align__(16) __bf16 As[128][32];
    __shared__ __align__(16) __bf16 Bs[128][32];
    int m0 = blockIdx.x * 128, n0 = blockIdx.y * 128;
    int t = threadIdx.x, w = t >> 6, l = t & 63;
    int lo = l & 15, hi = l >> 4;
    int wr = w >> 1, wc = w & 1;

    const __bf16* gA = A + (size_t)(m0 + w * 16 + (l >> 2)) * K + (l & 3) * 8;
    const __bf16* gB = W + (size_t)(n0 + w * 16 + (l >> 2)) * K + (l & 3) * 8;
    char* lA = (char*)&As[0][0] + w * 1024;
    char* lB = (char*)&Bs[0][0] + w * 1024;

    f32x4 acc[4][4] = {};
    for (int k0 = 0; k0 < K; k0 += 32) {
        gload_lds16(gA + k0, lA);
        gload_lds16(gA + 64 * K + k0, lA + 4096);
        gload_lds16(gB + k0, lB);
        gload_lds16(gB + 64 * K + k0, lB + 4096);
        __syncthreads();
        bf16x8 af[4], bq[4];
#pragma unroll
        for (int mi = 0; mi < 4; ++mi) af[mi] = *(const bf16x8*)&As[wr * 64 + mi * 16 + lo][hi * 8];
#pragma unroll
        for (int ni = 0; ni < 4; ++ni) bq[ni] = *(const bf16x8*)&Bs[wc * 64 + ni * 16 + lo][hi * 8];
#pragma unroll
        for (int mi = 0; mi < 4; ++mi)
#pragma unroll
            for (int ni = 0; ni < 4; ++ni)
                acc[mi][ni] = MFMA16(af[mi], bq[ni], acc[mi][ni]);
        __syncthreads();
    }

#pragma unroll
    for (int ni = 0; ni < 4; ++ni) {
        int n = n0 + wc * 64 + ni * 16 + lo;
        int h = n / 192, jj = n % 192, part = jj >> 6, d = jj & 63;
        float bn = bias[n];
#pragma unroll
        for (int mi = 0; mi < 4; ++mi)
#pragma unroll
            for (int j = 0; j < 4; ++j) {
                int m = m0 + wr * 64 + mi * 16 + hi * 4 + j;
                float v = acc[mi][ni][j] + bn;
                int b = m >> 10, s = m & 1023;
                size_t bh = (size_t)(b * 8 + h);
                if (part == 0)      q_ws[(bh * 1024 + s) * 64 + d] = (__bf16)(v * 0.125f);
                else if (part == 1) k_ws[(bh * 1024 + s) * 64 + d] = (__bf16)v;
                else                vt_ws[(bh * 64 + d) * 1024 + s] = (__bf16)v;
            }
    }
}

// ---------------- fused attention v7: v6 structure, PLAIN (non-nt) att stores ----------------
__global__ __launch_bounds__(256, 4) void k_attn(
    const __bf16* __restrict__ q_ws, const __bf16* __restrict__ k_ws,
    const __bf16* __restrict__ vt_ws,
    float* __restrict__ att_out, __bf16* __restrict__ values)
{
    __shared__ __align__(16) __bf16 Ps[4][16][272];  // 34,816 B (row stride 544B)
    __shared__ float Sred[4][16][2];                 //    512 B -> ~34.5 KB, 4 blk/CU

    int bid = blockIdx.x;                  // grid = 4096, XCD-bijective swizzle
    int nid = (bid & 7) * 512 + (bid >> 3);
    int bh = nid >> 6, qt = nid & 63;
    int q0 = qt * 16;
    int t = threadIdx.x, w = t >> 6, l = t & 63;
    int lo = l & 15, hi = l >> 4;

    // Q fragments straight from global (L2-hot), no LDS stage / no barrier
    const __bf16* Qg = q_ws + ((size_t)bh * 1024 + q0 + lo) * 64 + hi * 8;
    bf16x8 qa0 = *(const bf16x8*)Qg;
    bf16x8 qa1 = *(const bf16x8*)(Qg + 32);

    // QK^T into registers: lane holds S[q0 + hi*4 + j][w*256 + ct*16 + lo]
    const __bf16* Kb = k_ws + (size_t)bh * 65536;
    f32x4 acc[16];
#pragma unroll
    for (int ct = 0; ct < 16; ++ct) {
        const __bf16* kp = Kb + (size_t)(w * 256 + ct * 16 + lo) * 64 + hi * 8;
        bf16x8 kb0 = *(const bf16x8*)kp;
        bf16x8 kb1 = *(const bf16x8*)(kp + 32);
        f32x4 a = {};
        a = MFMA16(qa0, kb0, a);
        a = MFMA16(qa1, kb1, a);
        acc[ct] = a;
    }

    // wave-local stats over this wave's 256-col slice
    f32x4 mx = acc[0];
#pragma unroll
    for (int ct = 1; ct < 16; ++ct)
#pragma unroll
        for (int j = 0; j < 4; ++j) mx[j] = fmaxf(mx[j], acc[ct][j]);
#pragma unroll
    for (int off = 1; off < 16; off <<= 1)
#pragma unroll
        for (int j = 0; j < 4; ++j) mx[j] = fmaxf(mx[j], __shfl_xor(mx[j], off));

    f32x4 sum = {};
#pragma unroll
    for (int ct = 0; ct < 16; ++ct)
#pragma unroll
        for (int j = 0; j < 4; ++j) {
            acc[ct][j] = __expf(acc[ct][j] - mx[j]);
            sum[j] += acc[ct][j];
        }
#pragma unroll
    for (int off = 1; off < 16; off <<= 1)
#pragma unroll
        for (int j = 0; j < 4; ++j) sum[j] += __shfl_xor(sum[j], off);

    if (lo == 0) {
#pragma unroll
        for (int j = 0; j < 4; ++j) {
            Sred[w][hi * 4 + j][0] = mx[j];
            Sred[w][hi * 4 + j][1] = sum[j];
        }
    }
    __syncthreads();

    // full softmax scale for this wave's rows: exp(mx_w - gmx)/gsum
    f32x4 scale;
#pragma unroll
    for (int j = 0; j < 4; ++j) {
        int r = hi * 4 + j;
        float m0_ = Sred[0][r][0], m1_ = Sred[1][r][0], m2_ = Sred[2][r][0], m3_ = Sred[3][r][0];
        float gmx = fmaxf(fmaxf(m0_, m1_), fmaxf(m2_, m3_));
        float gsum = Sred[0][r][1] * __expf(m0_ - gmx) + Sred[1][r][1] * __expf(m1_ - gmx)
                   + Sred[2][r][1] * __expf(m2_ - gmx) + Sred[3][r][1] * __expf(m3_ - gmx);
        scale[j] = __expf(mx[j] - gmx) / gsum;
    }

    // Ps = FINAL probs (bf16)
#pragma unroll
    for (int ct = 0; ct < 16; ++ct)
#pragma unroll
        for (int j = 0; j < 4; ++j)
            Ps[w][hi * 4 + j][ct * 16 + lo] = (__bf16)(acc[ct][j] * scale[j]);
    __syncthreads();

    // PV by d: wave w -> d-cols [w*16, w*16+16), all 1024 k across the 4 Ps slices
    const __bf16* Vb = vt_ws + (size_t)bh * 65536 + (size_t)(w * 16 + lo) * 1024 + hi * 8;
    f32x4 oacc = {};
#pragma unroll
    for (int kc = 0; kc < 32; ++kc) {
        bf16x8 pa = *(const bf16x8*)&Ps[kc >> 3][lo][(kc & 7) * 32 + hi * 8];
        bf16x8 vb = *(const bf16x8*)(Vb + kc * 32);
        oacc = MFMA16(pa, vb, oacc);
    }
    int b = bh >> 3, h = bh & 7;
#pragma unroll
    for (int j = 0; j < 4; ++j)
        values[((size_t)b * 1024 + q0 + hi * 4 + j) * 512 + h * 64 + w * 16 + lo] = (__bf16)oacc[j];

    // attention f32 output: wave w -> rows [w*4, w*4+4), full-line coalesced PLAIN stores
#pragma unroll
    for (int rr = 0; rr < 4; ++rr) {
        int r = w * 4 + rr;
        float* gout = att_out + ((size_t)bh * 1024 + q0 + r) * 1024;
#pragma unroll
        for (int it = 0; it < 4; ++it) {
            bf16x4 pb = *(const bf16x4*)&Ps[it][r][l * 4];
            f32x4 p;
            p[0] = (float)pb[0]; p[1] = (float)pb[1];
            p[2] = (float)pb[2]; p[3] = (float)pb[3];
            *(f32x4*)&gout[it * 256 + l * 4] = p;   // A/B vs v6: nt removed
        }
    }
}

// ---------------- output GEMM (m97 structure): [8192x512] @ [512x512] + bias ----------------
__global__ __launch_bounds__(256) void k_out_gemm(
    const __bf16* __restrict__ A, const __bf16* __restrict__ W,
    const float* __restrict__ bias, float* __restrict__ out)
{
    const int K = 512;
    __shared__ __align__(16) __bf16 As[128][32];
    __shared__ __align__(16) __bf16 Bs[128][32];
    int m0 = blockIdx.x * 128, n0 = blockIdx.y * 128;
    int t = threadIdx.x, w = t >> 6, l = t & 63;
    int lo = l & 15, hi = l >> 4;
    int wr = w >> 1, wc = w & 1;

    const __bf16* gA = A + (size_t)(m0 + w * 16 + (l >> 2)) * K + (l & 3) * 8;
    const __bf16* gB = W + (size_t)(n0 + w * 16 + (l >> 2)) * K + (l & 3) * 8;
    char* lA = (char*)&As[0][0] + w * 1024;
    char* lB = (char*)&Bs[0][0] + w * 1024;

    f32x4 acc[4][4] = {};
    for (int k0 = 0; k0 < K; k0 += 32) {
        gload_lds16(gA + k0, lA);
        gload_lds16(gA + 64 * K + k0, lA + 4096);
        gload_lds16(gB + k0, lB);
        gload_lds16(gB + 64 * K + k0, lB + 4096);
        __syncthreads();
        bf16x8 af[4], bq[4];
#pragma unroll
        for (int mi = 0; mi < 4; ++mi) af[mi] = *(const bf16x8*)&As[wr * 64 + mi * 16 + lo][hi * 8];
#pragma unroll
        for (int ni = 0; ni < 4; ++ni) bq[ni] = *(const bf16x8*)&Bs[wc * 64 + ni * 16 + lo][hi * 8];
#pragma unroll
        for (int mi = 0; mi < 4; ++mi)
#pragma unroll
            for (int ni = 0; ni < 4; ++ni)
                acc[mi][ni] = MFMA16(af[mi], bq[ni], acc[mi][ni]);
        __syncthreads();
    }

#pragma unroll
    for (int ni = 0; ni < 4; ++ni) {
        int n = n0 + wc * 64 + ni * 16 + lo;
        float bn = bias[n];
#pragma unroll
        for (int mi = 0; mi < 4; ++mi)
#pragma unroll
            for (int j = 0; j < 4; ++j) {
                int m = m0 + wr * 64 + mi * 16 + hi * 4 + j;
                out[(size_t)m * 512 + n] = acc[mi][ni][j] + bn;
            }
    }
}

extern "C" void kernel_launch(void* const* d_in, const int* in_sizes, int n_in,
                              void* d_out, int out_size, void* d_ws, size_t ws_size,
                              hipStream_t stream)
{
    const float* x    = (const float*)d_in[0];
    const float* inp  = (const float*)d_in[1];
    const float* Wqkv = (const float*)d_in[2];
    const float* bqkv = (const float*)d_in[3];
    const float* Wo   = (const float*)d_in[4];
    const float* bo   = (const float*)d_in[5];

    float* out_o   = (float*)d_out;                    // [8,1024,512]
    float* out_att = out_o + (size_t)8 * 1024 * 512;   // [8,8,1024,1024]

    char* ws = (char*)d_ws;
    __bf16* xc    = (__bf16*)(ws + 0);
    __bf16* wq    = (__bf16*)(ws + 9437184);
    __bf16* wo    = (__bf16*)(ws + 11206656);
    __bf16* q_ws  = (__bf16*)(ws + 11730944);
    __bf16* k_ws  = (__bf16*)(ws + 20119552);
    __bf16* vt_ws = (__bf16*)(ws + 28508160);
    __bf16* vals  = (__bf16*)(ws + 36896768);

    k_convert<<<2864, 256, 0, stream>>>(x, inp, Wqkv, Wo, xc, wq, wo);
    k_qkv_gemm<<<dim3(64, 12), 256, 0, stream>>>(xc, wq, bqkv, q_ws, k_ws, vt_ws);
    k_attn<<<4096, 256, 0, stream>>>(q_ws, k_ws, vt_ws, out_att, vals);
    k_out_gemm<<<dim3(64, 4), 256, 0, stream>>>(vals, wo, bo, out_o);
}

// Round 8
// 180.052 us; speedup vs baseline: 1.0374x; 1.0374x over previous
//
#include <hip/hip_runtime.h>

typedef __bf16 bf16x8 __attribute__((ext_vector_type(8)));
typedef __bf16 bf16x4 __attribute__((ext_vector_type(4)));
typedef float f32x4 __attribute__((ext_vector_type(4)));

#define MFMA16(a,b,c) __builtin_amdgcn_mfma_f32_16x16x32_bf16((a),(b),(c),0,0,0)

__device__ __forceinline__ void gload_lds16(const void* g, void* l) {
    __builtin_amdgcn_global_load_lds(
        (const __attribute__((address_space(1))) void*)g,
        (__attribute__((address_space(3))) void*)l, 16, 0, 0);
}

// Problem constants: B=8 S=1024 IN=512 ORIG=64 E=512 H=8 hd=64
// xc: [8192][576]  Wqkv: [1536][576]  Wo: [512][512]
// q_ws/k_ws: [64(bh)][1024(s)][64(d)] bf16 ; vt_ws: [64(bh)][64(d)][1024(s)] bf16

__global__ __launch_bounds__(256) void k_convert(
    const float* __restrict__ x, const float* __restrict__ inp,
    const float* __restrict__ Wqkv, const float* __restrict__ Wo,
    __bf16* __restrict__ xc, __bf16* __restrict__ wq, __bf16* __restrict__ wo)
{
    const unsigned C1 = 589824u;   // 8192*576/8
    const unsigned C2 = 110592u;   // 1536*576/8
    unsigned i = blockIdx.x * 256u + threadIdx.x;   // 8-element chunk index
    if (i < C1) {
        unsigned e = i * 8u;
        unsigned m = e / 576u, k = e - m * 576u;
        const float* p = (k < 512u) ? x + (size_t)m * 512u + k
                                    : inp + (size_t)m * 64u + (k - 512u);
        f32x4 a = *(const f32x4*)p, b = *(const f32x4*)(p + 4);
        bf16x8 o;
#pragma unroll
        for (int j = 0; j < 4; ++j) { o[j] = (__bf16)a[j]; o[j + 4] = (__bf16)b[j]; }
        *(bf16x8*)&xc[e] = o;
    } else if (i < C1 + C2) {
        unsigned e = (i - C1) * 8u;
        f32x4 a = *(const f32x4*)&Wqkv[e], b = *(const f32x4*)&Wqkv[e + 4];
        bf16x8 o;
#pragma unroll
        for (int j = 0; j < 4; ++j) { o[j] = (__bf16)a[j]; o[j + 4] = (__bf16)b[j]; }
        *(bf16x8*)&wq[e] = o;
    } else {
        unsigned e = (i - C1 - C2) * 8u;
        f32x4 a = *(const f32x4*)&Wo[e], b = *(const f32x4*)&Wo[e + 4];
        bf16x8 o;
#pragma unroll
        for (int j = 0; j < 4; ++j) { o[j] = (__bf16)a[j]; o[j + 4] = (__bf16)b[j]; }
        *(bf16x8*)&wo[e] = o;
    }
}

// ---------------- QKV GEMM (m97 structure): 128x128 tile, BK=32, global_load_lds ----------------
__global__ __launch_bounds__(256) void k_qkv_gemm(
    const __bf16* __restrict__ A, const __bf16* __restrict__ W,
    const float* __restrict__ bias,
    __bf16* __restrict__ q_ws, __bf16* __restrict__ k_ws, __bf16* __restrict__ vt_ws)
{
    const int K = 576;
    __shared__ __align__(16) __bf16 As[128][32];
    __shared__ __align__(16) __bf16 Bs[128][32];
    int m0 = blockIdx.x * 128, n0 = blockIdx.y * 128;
    int t = threadIdx.x, w = t >> 6, l = t & 63;
    int lo = l & 15, hi = l >> 4;
    int wr = w >> 1, wc = w & 1;

    const __bf16* gA = A + (size_t)(m0 + w * 16 + (l >> 2)) * K + (l & 3) * 8;
    const __bf16* gB = W + (size_t)(n0 + w * 16 + (l >> 2)) * K + (l & 3) * 8;
    char* lA = (char*)&As[0][0] + w * 1024;
    char* lB = (char*)&Bs[0][0] + w * 1024;

    f32x4 acc[4][4] = {};
    for (int k0 = 0; k0 < K; k0 += 32) {
        gload_lds16(gA + k0, lA);
        gload_lds16(gA + 64 * K + k0, lA + 4096);
        gload_lds16(gB + k0, lB);
        gload_lds16(gB + 64 * K + k0, lB + 4096);
        __syncthreads();
        bf16x8 af[4], bq[4];
#pragma unroll
        for (int mi = 0; mi < 4; ++mi) af[mi] = *(const bf16x8*)&As[wr * 64 + mi * 16 + lo][hi * 8];
#pragma unroll
        for (int ni = 0; ni < 4; ++ni) bq[ni] = *(const bf16x8*)&Bs[wc * 64 + ni * 16 + lo][hi * 8];
#pragma unroll
        for (int mi = 0; mi < 4; ++mi)
#pragma unroll
            for (int ni = 0; ni < 4; ++ni)
                acc[mi][ni] = MFMA16(af[mi], bq[ni], acc[mi][ni]);
        __syncthreads();
    }

#pragma unroll
    for (int ni = 0; ni < 4; ++ni) {
        int n = n0 + wc * 64 + ni * 16 + lo;
        int h = n / 192, jj = n % 192, part = jj >> 6, d = jj & 63;
        float bn = bias[n];
#pragma unroll
        for (int mi = 0; mi < 4; ++mi)
#pragma unroll
            for (int j = 0; j < 4; ++j) {
                int m = m0 + wr * 64 + mi * 16 + hi * 4 + j;
                float v = acc[mi][ni][j] + bn;
                int b = m >> 10, s = m & 1023;
                size_t bh = (size_t)(b * 8 + h);
                if (part == 0)      q_ws[(bh * 1024 + s) * 64 + d] = (__bf16)(v * 0.125f);
                else if (part == 1) k_ws[(bh * 1024 + s) * 64 + d] = (__bf16)v;
                else                vt_ws[(bh * 64 + d) * 1024 + s] = (__bf16)v;
            }
    }
}

// ---------------- fused attention v8: att-store BEFORE PV (stores drain under MFMA) ----------------
__global__ __launch_bounds__(256, 4) void k_attn(
    const __bf16* __restrict__ q_ws, const __bf16* __restrict__ k_ws,
    const __bf16* __restrict__ vt_ws,
    float* __restrict__ att_out, __bf16* __restrict__ values)
{
    __shared__ __align__(16) __bf16 Ps[4][16][280];  // 35,840 B (row stride 560B: 4-way max)
    __shared__ float Sred[4][16][2];                 //    512 B -> ~36 KB, 4 blk/CU

    int bid = blockIdx.x;                  // grid = 4096, XCD-bijective swizzle
    int nid = (bid & 7) * 512 + (bid >> 3);
    int bh = nid >> 6, qt = nid & 63;
    int q0 = qt * 16;
    int t = threadIdx.x, w = t >> 6, l = t & 63;
    int lo = l & 15, hi = l >> 4;

    // Q fragments straight from global (L2-hot)
    const __bf16* Qg = q_ws + ((size_t)bh * 1024 + q0 + lo) * 64 + hi * 8;
    bf16x8 qa0 = *(const bf16x8*)Qg;
    bf16x8 qa1 = *(const bf16x8*)(Qg + 32);

    // QK^T into registers: lane holds S[q0 + hi*4 + j][w*256 + ct*16 + lo]
    const __bf16* Kb = k_ws + (size_t)bh * 65536;
    f32x4 acc[16];
#pragma unroll
    for (int ct = 0; ct < 16; ++ct) {
        const __bf16* kp = Kb + (size_t)(w * 256 + ct * 16 + lo) * 64 + hi * 8;
        bf16x8 kb0 = *(const bf16x8*)kp;
        bf16x8 kb1 = *(const bf16x8*)(kp + 32);
        f32x4 a = {};
        a = MFMA16(qa0, kb0, a);
        a = MFMA16(qa1, kb1, a);
        acc[ct] = a;
    }

    // wave-local stats over this wave's 256-col slice
    f32x4 mx = acc[0];
#pragma unroll
    for (int ct = 1; ct < 16; ++ct)
#pragma unroll
        for (int j = 0; j < 4; ++j) mx[j] = fmaxf(mx[j], acc[ct][j]);
#pragma unroll
    for (int off = 1; off < 16; off <<= 1)
#pragma unroll
        for (int j = 0; j < 4; ++j) mx[j] = fmaxf(mx[j], __shfl_xor(mx[j], off));

    f32x4 sum = {};
#pragma unroll
    for (int ct = 0; ct < 16; ++ct)
#pragma unroll
        for (int j = 0; j < 4; ++j) {
            acc[ct][j] = __expf(acc[ct][j] - mx[j]);
            sum[j] += acc[ct][j];
        }
#pragma unroll
    for (int off = 1; off < 16; off <<= 1)
#pragma unroll
        for (int j = 0; j < 4; ++j) sum[j] += __shfl_xor(sum[j], off);

    if (lo == 0) {
#pragma unroll
        for (int j = 0; j < 4; ++j) {
            Sred[w][hi * 4 + j][0] = mx[j];
            Sred[w][hi * 4 + j][1] = sum[j];
        }
    }
    __syncthreads();

    // full softmax scale for this wave's rows: exp(mx_w - gmx)/gsum
    f32x4 scale;
#pragma unroll
    for (int j = 0; j < 4; ++j) {
        int r = hi * 4 + j;
        float m0_ = Sred[0][r][0], m1_ = Sred[1][r][0], m2_ = Sred[2][r][0], m3_ = Sred[3][r][0];
        float gmx = fmaxf(fmaxf(m0_, m1_), fmaxf(m2_, m3_));
        float gsum = Sred[0][r][1] * __expf(m0_ - gmx) + Sred[1][r][1] * __expf(m1_ - gmx)
                   + Sred[2][r][1] * __expf(m2_ - gmx) + Sred[3][r][1] * __expf(m3_ - gmx);
        scale[j] = __expf(mx[j] - gmx) / gsum;
    }

    // Ps = FINAL probs (bf16)
#pragma unroll
    for (int ct = 0; ct < 16; ++ct)
#pragma unroll
        for (int j = 0; j < 4; ++j)
            Ps[w][hi * 4 + j][ct * 16 + lo] = (__bf16)(acc[ct][j] * scale[j]);
    __syncthreads();

    // attention f32 output FIRST: fire-and-forget nt stores that drain under PV's MFMA phase
#pragma unroll
    for (int rr = 0; rr < 4; ++rr) {
        int r = w * 4 + rr;
        float* gout = att_out + ((size_t)bh * 1024 + q0 + r) * 1024;
#pragma unroll
        for (int it = 0; it < 4; ++it) {
            bf16x4 pb = *(const bf16x4*)&Ps[it][r][l * 4];
            f32x4 p;
            p[0] = (float)pb[0]; p[1] = (float)pb[1];
            p[2] = (float)pb[2]; p[3] = (float)pb[3];
            __builtin_nontemporal_store(p, (f32x4*)&gout[it * 256 + l * 4]);
        }
    }

    // PV by d: wave w -> d-cols [w*16, w*16+16), all 1024 k across the 4 Ps slices
    const __bf16* Vb = vt_ws + (size_t)bh * 65536 + (size_t)(w * 16 + lo) * 1024 + hi * 8;
    f32x4 oacc = {};
#pragma unroll
    for (int kc = 0; kc < 32; ++kc) {
        bf16x8 pa = *(const bf16x8*)&Ps[kc >> 3][lo][(kc & 7) * 32 + hi * 8];
        bf16x8 vb = *(const bf16x8*)(Vb + kc * 32);
        oacc = MFMA16(pa, vb, oacc);
    }
    int b = bh >> 3, h = bh & 7;
#pragma unroll
    for (int j = 0; j < 4; ++j)
        values[((size_t)b * 1024 + q0 + hi * 4 + j) * 512 + h * 64 + w * 16 + lo] = (__bf16)oacc[j];
}

// ---------------- output GEMM (m97 structure): [8192x512] @ [512x512] + bias ----------------
__global__ __launch_bounds__(256) void k_out_gemm(
    const __bf16* __restrict__ A, const __bf16* __restrict__ W,
    const float* __restrict__ bias, float* __restrict__ out)
{
    const int K = 512;
    __shared__ __align__(16) __bf16 As[128][32];
    __shared__ __align__(16) __bf16 Bs[128][32];
    int m0 = blockIdx.x * 128, n0 = blockIdx.y * 128;
    int t = threadIdx.x, w = t >> 6, l = t & 63;
    int lo = l & 15, hi = l >> 4;
    int wr = w >> 1, wc = w & 1;

    const __bf16* gA = A + (size_t)(m0 + w * 16 + (l >> 2)) * K + (l & 3) * 8;
    const __bf16* gB = W + (size_t)(n0 + w * 16 + (l >> 2)) * K + (l & 3) * 8;
    char* lA = (char*)&As[0][0] + w * 1024;
    char* lB = (char*)&Bs[0][0] + w * 1024;

    f32x4 acc[4][4] = {};
    for (int k0 = 0; k0 < K; k0 += 32) {
        gload_lds16(gA + k0, lA);
        gload_lds16(gA + 64 * K + k0, lA + 4096);
        gload_lds16(gB + k0, lB);
        gload_lds16(gB + 64 * K + k0, lB + 4096);
        __syncthreads();
        bf16x8 af[4], bq[4];
#pragma unroll
        for (int mi = 0; mi < 4; ++mi) af[mi] = *(const bf16x8*)&As[wr * 64 + mi * 16 + lo][hi * 8];
#pragma unroll
        for (int ni = 0; ni < 4; ++ni) bq[ni] = *(const bf16x8*)&Bs[wc * 64 + ni * 16 + lo][hi * 8];
#pragma unroll
        for (int mi = 0; mi < 4; ++mi)
#pragma unroll
            for (int ni = 0; ni < 4; ++ni)
                acc[mi][ni] = MFMA16(af[mi], bq[ni], acc[mi][ni]);
        __syncthreads();
    }

#pragma unroll
    for (int ni = 0; ni < 4; ++ni) {
        int n = n0 + wc * 64 + ni * 16 + lo;
        float bn = bias[n];
#pragma unroll
        for (int mi = 0; mi < 4; ++mi)
#pragma unroll
            for (int j = 0; j < 4; ++j) {
                int m = m0 + wr * 64 + mi * 16 + hi * 4 + j;
                out[(size_t)m * 512 + n] = acc[mi][ni][j] + bn;
            }
    }
}

extern "C" void kernel_launch(void* const* d_in, const int* in_sizes, int n_in,
                              void* d_out, int out_size, void* d_ws, size_t ws_size,
                              hipStream_t stream)
{
    const float* x    = (const float*)d_in[0];
    const float* inp  = (const float*)d_in[1];
    const float* Wqkv = (const float*)d_in[2];
    const float* bqkv = (const float*)d_in[3];
    const float* Wo   = (const float*)d_in[4];
    const float* bo   = (const float*)d_in[5];

    float* out_o   = (float*)d_out;                    // [8,1024,512]
    float* out_att = out_o + (size_t)8 * 1024 * 512;   // [8,8,1024,1024]

    char* ws = (char*)d_ws;
    __bf16* xc    = (__bf16*)(ws + 0);
    __bf16* wq    = (__bf16*)(ws + 9437184);
    __bf16* wo    = (__bf16*)(ws + 11206656);
    __bf16* q_ws  = (__bf16*)(ws + 11730944);
    __bf16* k_ws  = (__bf16*)(ws + 20119552);
    __bf16* vt_ws = (__bf16*)(ws + 28508160);
    __bf16* vals  = (__bf16*)(ws + 36896768);

    k_convert<<<2864, 256, 0, stream>>>(x, inp, Wqkv, Wo, xc, wq, wo);
    k_qkv_gemm<<<dim3(64, 12), 256, 0, stream>>>(xc, wq, bqkv, q_ws, k_ws, vt_ws);
    k_attn<<<4096, 256, 0, stream>>>(q_ws, k_ws, vt_ws, out_att, vals);
    k_out_gemm<<<dim3(64, 4), 256, 0, stream>>>(vals, wo, bo, out_o);
}

// Round 10
// 132.320 us; speedup vs baseline: 1.4117x; 1.3607x over previous
//
#include <hip/hip_runtime.h>

typedef __bf16 bf16x8 __attribute__((ext_vector_type(8)));
typedef __bf16 bf16x4 __attribute__((ext_vector_type(4)));
typedef float f32x4 __attribute__((ext_vector_type(4)));

#define MFMA16(a,b,c) __builtin_amdgcn_mfma_f32_16x16x32_bf16((a),(b),(c),0,0,0)

__device__ __forceinline__ void gload_lds16(const void* g, void* l) {
    __builtin_amdgcn_global_load_lds(
        (const __attribute__((address_space(1))) void*)g,
        (__attribute__((address_space(3))) void*)l, 16, 0, 0);
}

// Problem constants: B=8 S=1024 IN=512 ORIG=64 E=512 H=8 hd=64
// xc: [8192][576]  Wqkv: [1536][576]  Wo: [512][512]
// q_ws/k_ws: [64(bh)][1024(s)][64(d)] bf16 ; vt_ws: [64(bh)][64(d)][1024(s)] bf16

__global__ __launch_bounds__(256) void k_convert(
    const float* __restrict__ x, const float* __restrict__ inp,
    const float* __restrict__ Wqkv, const float* __restrict__ Wo,
    __bf16* __restrict__ xc, __bf16* __restrict__ wq, __bf16* __restrict__ wo)
{
    const unsigned C1 = 589824u;   // 8192*576/8
    const unsigned C2 = 110592u;   // 1536*576/8
    unsigned i = blockIdx.x * 256u + threadIdx.x;   // 8-element chunk index
    if (i < C1) {
        unsigned e = i * 8u;
        unsigned m = e / 576u, k = e - m * 576u;
        const float* p = (k < 512u) ? x + (size_t)m * 512u + k
                                    : inp + (size_t)m * 64u + (k - 512u);
        f32x4 a = *(const f32x4*)p, b = *(const f32x4*)(p + 4);
        bf16x8 o;
#pragma unroll
        for (int j = 0; j < 4; ++j) { o[j] = (__bf16)a[j]; o[j + 4] = (__bf16)b[j]; }
        *(bf16x8*)&xc[e] = o;
    } else if (i < C1 + C2) {
        unsigned e = (i - C1) * 8u;
        f32x4 a = *(const f32x4*)&Wqkv[e], b = *(const f32x4*)&Wqkv[e + 4];
        bf16x8 o;
#pragma unroll
        for (int j = 0; j < 4; ++j) { o[j] = (__bf16)a[j]; o[j + 4] = (__bf16)b[j]; }
        *(bf16x8*)&wq[e] = o;
    } else {
        unsigned e = (i - C1 - C2) * 8u;
        f32x4 a = *(const f32x4*)&Wo[e], b = *(const f32x4*)&Wo[e + 4];
        bf16x8 o;
#pragma unroll
        for (int j = 0; j < 4; ++j) { o[j] = (__bf16)a[j]; o[j + 4] = (__bf16)b[j]; }
        *(bf16x8*)&wo[e] = o;
    }
}

// ---------------- QKV GEMM (m97 structure): 128x128 tile, BK=32, global_load_lds ----------------
__global__ __launch_bounds__(256) void k_qkv_gemm(
    const __bf16* __restrict__ A, const __bf16* __restrict__ W,
    const float* __restrict__ bias,
    __bf16* __restrict__ q_ws, __bf16* __restrict__ k_ws, __bf16* __restrict__ vt_ws)
{
    const int K = 576;
    __shared__ __align__(16) __bf16 As[128][32];
    __shared__ __align__(16) __bf16 Bs[128][32];
    int m0 = blockIdx.x * 128, n0 = blockIdx.y * 128;
    int t = threadIdx.x, w = t >> 6, l = t & 63;
    int lo = l & 15, hi = l >> 4;
    int wr = w >> 1, wc = w & 1;

    const __bf16* gA = A + (size_t)(m0 + w * 16 + (l >> 2)) * K + (l & 3) * 8;
    const __bf16* gB = W + (size_t)(n0 + w * 16 + (l >> 2)) * K + (l & 3) * 8;
    char* lA = (char*)&As[0][0] + w * 1024;
    char* lB = (char*)&Bs[0][0] + w * 1024;

    f32x4 acc[4][4] = {};
    for (int k0 = 0; k0 < K; k0 += 32) {
        gload_lds16(gA + k0, lA);
        gload_lds16(gA + 64 * K + k0, lA + 4096);
        gload_lds16(gB + k0, lB);
        gload_lds16(gB + 64 * K + k0, lB + 4096);
        __syncthreads();
        bf16x8 af[4], bq[4];
#pragma unroll
        for (int mi = 0; mi < 4; ++mi) af[mi] = *(const bf16x8*)&As[wr * 64 + mi * 16 + lo][hi * 8];
#pragma unroll
        for (int ni = 0; ni < 4; ++ni) bq[ni] = *(const bf16x8*)&Bs[wc * 64 + ni * 16 + lo][hi * 8];
#pragma unroll
        for (int mi = 0; mi < 4; ++mi)
#pragma unroll
            for (int ni = 0; ni < 4; ++ni)
                acc[mi][ni] = MFMA16(af[mi], bq[ni], acc[mi][ni]);
        __syncthreads();
    }

#pragma unroll
    for (int ni = 0; ni < 4; ++ni) {
        int n = n0 + wc * 64 + ni * 16 + lo;
        int h = n / 192, jj = n % 192, part = jj >> 6, d = jj & 63;
        float bn = bias[n];
#pragma unroll
        for (int mi = 0; mi < 4; ++mi)
#pragma unroll
            for (int j = 0; j < 4; ++j) {
                int m = m0 + wr * 64 + mi * 16 + hi * 4 + j;
                float v = acc[mi][ni][j] + bn;
                int b = m >> 10, s = m & 1023;
                size_t bh = (size_t)(b * 8 + h);
                if (part == 0)      q_ws[(bh * 1024 + s) * 64 + d] = (__bf16)(v * 0.125f);
                else if (part == 1) k_ws[(bh * 1024 + s) * 64 + d] = (__bf16)v;
                else                vt_ws[(bh * 64 + d) * 1024 + s] = (__bf16)v;
            }
    }
}

// ---------------- fused attention v10: QBLK=64, 2-pass (online LSE + emit/PV), d-split PV ----------------
__global__ __launch_bounds__(256, 4) void k_attn(
    const __bf16* __restrict__ q_ws, const __bf16* __restrict__ k_ws,
    const __bf16* __restrict__ vt_ws,
    float* __restrict__ att_out, __bf16* __restrict__ values)
{
    __shared__ __align__(16) __bf16 Klds[2][64][76];     // 19,456 B
    __shared__ __align__(16) __bf16 Pl[2][4][16][76];    // 19,456 B -> 38 KB, 4 blk/CU

    int bid = blockIdx.x;                    // grid = 1024 (64 bh x 16 q-tiles of 64 rows)
    int nid = (bid & 7) * 128 + (bid >> 3);  // bijective XCD swizzle
    int bh = nid >> 4, qt = nid & 15;
    int t = threadIdx.x, w = t >> 6, l = t & 63;
    int lo = l & 15, hi = l >> 4;
    int q0 = qt * 64 + w * 16;               // wave owns 16 FULL rows (QK^T + softmax)

    const __bf16* Qg = q_ws + ((size_t)bh * 1024 + q0 + lo) * 64 + hi * 8;
    bf16x8 qa0 = *(const bf16x8*)Qg;
    bf16x8 qa1 = *(const bf16x8*)(Qg + 32);

    // K staging: thread t -> row t>>2, cols (t&3)*16..+16 of the 64-row chunk
    const __bf16* Kb = k_ws + (size_t)bh * 65536;
    int srow = t >> 2, scol = (t & 3) * 16;
    const __bf16* gK = Kb + (size_t)srow * 64 + scol;
    bf16x8 r0, r1;

#define STAGE_LOAD(c)  { const __bf16* p_ = gK + (size_t)(c) * 4096; \
                         r0 = *(const bf16x8*)p_; r1 = *(const bf16x8*)(p_ + 8); }
#define STAGE_WRITE(b) { *(bf16x8*)&Klds[b][srow][scol] = r0; \
                         *(bf16x8*)&Klds[b][srow][scol + 8] = r1; }
#define SCHUNK(b, s)   _Pragma("unroll") \
                       for (int kk = 0; kk < 4; ++kk) { \
                           bf16x8 kb0 = *(const bf16x8*)&Klds[b][kk * 16 + lo][hi * 8]; \
                           bf16x8 kb1 = *(const bf16x8*)&Klds[b][kk * 16 + lo][hi * 8 + 32]; \
                           f32x4 a_ = {}; \
                           a_ = MFMA16(qa0, kb0, a_); \
                           a_ = MFMA16(qa1, kb1, a_); \
                           s[kk] = a_; \
                       }

    // ---- pass A: online (max, sum) per lane over its col-subset; no O-rescale ----
    f32x4 lmx = { -3.4e38f, -3.4e38f, -3.4e38f, -3.4e38f };
    f32x4 lsum = {};
    STAGE_LOAD(0); STAGE_WRITE(0);
    __syncthreads();
    for (int c = 0; c < 16; ++c) {
        if (c < 15) STAGE_LOAD(c + 1);
        f32x4 s[4];
        SCHUNK(c & 1, s);
#pragma unroll
        for (int j = 0; j < 4; ++j) {
            float cm = fmaxf(fmaxf(s[0][j], s[1][j]), fmaxf(s[2][j], s[3][j]));
            float nm = fmaxf(lmx[j], cm);
            float a = __expf(s[0][j] - nm) + __expf(s[1][j] - nm)
                    + __expf(s[2][j] - nm) + __expf(s[3][j] - nm);
            lsum[j] = lsum[j] * __expf(lmx[j] - nm) + a;
            lmx[j] = nm;
        }
        if (c < 15) STAGE_WRITE((c + 1) & 1);
        __syncthreads();
    }
    // combine across the 16 lanes of the lo-group
    f32x4 gmx = lmx;
#pragma unroll
    for (int off = 1; off < 16; off <<= 1)
#pragma unroll
        for (int j = 0; j < 4; ++j) gmx[j] = fmaxf(gmx[j], __shfl_xor(gmx[j], off));
    f32x4 part;
#pragma unroll
    for (int j = 0; j < 4; ++j) part[j] = lsum[j] * __expf(lmx[j] - gmx[j]);
#pragma unroll
    for (int off = 1; off < 16; off <<= 1)
#pragma unroll
        for (int j = 0; j < 4; ++j) part[j] += __shfl_xor(part[j], off);
    f32x4 ginv;
#pragma unroll
    for (int j = 0; j < 4; ++j) ginv[j] = 1.f / part[j];

    // ---- pass B: recompute S, emit att (f32, spread), Pl bf16; PV lagged 1 chunk, d-split ----
    float* gattW = att_out + ((size_t)bh * 1024 + q0) * 1024;
    const __bf16* Vb = vt_ws + (size_t)bh * 65536 + (size_t)(w * 16 + lo) * 1024 + hi * 8;
    f32x4 oacc[4] = {};   // row-group g of the 64-row block, d = w*16+lo

    STAGE_LOAD(0); STAGE_WRITE(0);
    __syncthreads();
    for (int c = 0; c < 16; ++c) {
        if (c < 15) STAGE_LOAD(c + 1);
        f32x4 s[4];
        SCHUNK(c & 1, s);
#pragma unroll
        for (int kk = 0; kk < 4; ++kk)
#pragma unroll
            for (int j = 0; j < 4; ++j) {
                float p = __expf(s[kk][j] - gmx[j]) * ginv[j];
                gattW[(size_t)(hi * 4 + j) * 1024 + c * 64 + kk * 16 + lo] = p;
                Pl[c & 1][w][hi * 4 + j][kk * 16 + lo] = (__bf16)p;
            }
        if (c > 0) {   // PV for chunk c-1 (Pl visible since last barrier)
            int pb = (c - 1) & 1;
            const __bf16* vp = Vb + (size_t)(c - 1) * 64;
            bf16x8 vb0 = *(const bf16x8*)vp;
            bf16x8 vb1 = *(const bf16x8*)(vp + 32);
#pragma unroll
            for (int g = 0; g < 4; ++g) {
                bf16x8 pa0 = *(const bf16x8*)&Pl[pb][g][lo][hi * 8];
                bf16x8 pa1 = *(const bf16x8*)&Pl[pb][g][lo][hi * 8 + 32];
                oacc[g] = MFMA16(pa0, vb0, oacc[g]);
                oacc[g] = MFMA16(pa1, vb1, oacc[g]);
            }
        }
        if (c < 15) STAGE_WRITE((c + 1) & 1);
        __syncthreads();
    }
    {   // final PV: chunk 15 (Pl[1], visible after the loop's last barrier)
        const __bf16* vp = Vb + (size_t)15 * 64;
        bf16x8 vb0 = *(const bf16x8*)vp;
        bf16x8 vb1 = *(const bf16x8*)(vp + 32);
#pragma unroll
        for (int g = 0; g < 4; ++g) {
            bf16x8 pa0 = *(const bf16x8*)&Pl[1][g][lo][hi * 8];
            bf16x8 pa1 = *(const bf16x8*)&Pl[1][g][lo][hi * 8 + 32];
            oacc[g] = MFMA16(pa0, vb0, oacc[g]);
            oacc[g] = MFMA16(pa1, vb1, oacc[g]);
        }
    }

    int b = bh >> 3, h = bh & 7;
#pragma unroll
    for (int g = 0; g < 4; ++g)
#pragma unroll
        for (int j = 0; j < 4; ++j)
            values[((size_t)b * 1024 + qt * 64 + g * 16 + hi * 4 + j) * 512
                   + h * 64 + w * 16 + lo] = (__bf16)oacc[g][j];
#undef STAGE_LOAD
#undef STAGE_WRITE
#undef SCHUNK
}

// ---------------- output GEMM (m97 structure): [8192x512] @ [512x512] + bias ----------------
__global__ __launch_bounds__(256) void k_out_gemm(
    const __bf16* __restrict__ A, const __bf16* __restrict__ W,
    const float* __restrict__ bias, float* __restrict__ out)
{
    const int K = 512;
    __shared__ __align__(16) __bf16 As[128][32];
    __shared__ __align__(16) __bf16 Bs[128][32];
    int m0 = blockIdx.x * 128, n0 = blockIdx.y * 128;
    int t = threadIdx.x, w = t >> 6, l = t & 63;
    int lo = l & 15, hi = l >> 4;
    int wr = w >> 1, wc = w & 1;

    const __bf16* gA = A + (size_t)(m0 + w * 16 + (l >> 2)) * K + (l & 3) * 8;
    const __bf16* gB = W + (size_t)(n0 + w * 16 + (l >> 2)) * K + (l & 3) * 8;
    char* lA = (char*)&As[0][0] + w * 1024;
    char* lB = (char*)&Bs[0][0] + w * 1024;

    f32x4 acc[4][4] = {};
    for (int k0 = 0; k0 < K; k0 += 32) {
        gload_lds16(gA + k0, lA);
        gload_lds16(gA + 64 * K + k0, lA + 4096);
        gload_lds16(gB + k0, lB);
        gload_lds16(gB + 64 * K + k0, lB + 4096);
        __syncthreads();
        bf16x8 af[4], bq[4];
#pragma unroll
        for (int mi = 0; mi < 4; ++mi) af[mi] = *(const bf16x8*)&As[wr * 64 + mi * 16 + lo][hi * 8];
#pragma unroll
        for (int ni = 0; ni < 4; ++ni) bq[ni] = *(const bf16x8*)&Bs[wc * 64 + ni * 16 + lo][hi * 8];
#pragma unroll
        for (int mi = 0; mi < 4; ++mi)
#pragma unroll
            for (int ni = 0; ni < 4; ++ni)
                acc[mi][ni] = MFMA16(af[mi], bq[ni], acc[mi][ni]);
        __syncthreads();
    }

#pragma unroll
    for (int ni = 0; ni < 4; ++ni) {
        int n = n0 + wc * 64 + ni * 16 + lo;
        float bn = bias[n];
#pragma unroll
        for (int mi = 0; mi < 4; ++mi)
#pragma unroll
            for (int j = 0; j < 4; ++j) {
                int m = m0 + wr * 64 + mi * 16 + hi * 4 + j;
                out[(size_t)m * 512 + n] = acc[mi][ni][j] + bn;
            }
    }
}

extern "C" void kernel_launch(void* const* d_in, const int* in_sizes, int n_in,
                              void* d_out, int out_size, void* d_ws, size_t ws_size,
                              hipStream_t stream)
{
    const float* x    = (const float*)d_in[0];
    const float* inp  = (const float*)d_in[1];
    const float* Wqkv = (const float*)d_in[2];
    const float* bqkv = (const float*)d_in[3];
    const float* Wo   = (const float*)d_in[4];
    const float* bo   = (const float*)d_in[5];

    float* out_o   = (float*)d_out;                    // [8,1024,512]
    float* out_att = out_o + (size_t)8 * 1024 * 512;   // [8,8,1024,1024]

    char* ws = (char*)d_ws;
    __bf16* xc    = (__bf16*)(ws + 0);
    __bf16* wq    = (__bf16*)(ws + 9437184);
    __bf16* wo    = (__bf16*)(ws + 11206656);
    __bf16* q_ws  = (__bf16*)(ws + 11730944);
    __bf16* k_ws  = (__bf16*)(ws + 20119552);
    __bf16* vt_ws = (__bf16*)(ws + 28508160);
    __bf16* vals  = (__bf16*)(ws + 36896768);

    k_convert<<<2864, 256, 0, stream>>>(x, inp, Wqkv, Wo, xc, wq, wo);
    k_qkv_gemm<<<dim3(64, 12), 256, 0, stream>>>(xc, wq, bqkv, q_ws, k_ws, vt_ws);
    k_attn<<<1024, 256, 0, stream>>>(q_ws, k_ws, vt_ws, out_att, vals);
    k_out_gemm<<<dim3(64, 4), 256, 0, stream>>>(vals, wo, bo, out_o);
}

// Round 11
// 131.233 us; speedup vs baseline: 1.4234x; 1.0083x over previous
//
#include <hip/hip_runtime.h>

typedef __bf16 bf16x8 __attribute__((ext_vector_type(8)));
typedef __bf16 bf16x4 __attribute__((ext_vector_type(4)));
typedef float f32x4 __attribute__((ext_vector_type(4)));

#define MFMA16(a,b,c) __builtin_amdgcn_mfma_f32_16x16x32_bf16((a),(b),(c),0,0,0)

__device__ __forceinline__ void gload_lds16(const void* g, void* l) {
    __builtin_amdgcn_global_load_lds(
        (const __attribute__((address_space(1))) void*)g,
        (__attribute__((address_space(3))) void*)l, 16, 0, 0);
}

// Problem constants: B=8 S=1024 IN=512 ORIG=64 E=512 H=8 hd=64

__global__ __launch_bounds__(256) void k_convert(
    const float* __restrict__ x, const float* __restrict__ inp,
    const float* __restrict__ Wqkv, const float* __restrict__ Wo,
    __bf16* __restrict__ xc, __bf16* __restrict__ wq, __bf16* __restrict__ wo)
{
    const unsigned C1 = 589824u;   // 8192*576/8
    const unsigned C2 = 110592u;   // 1536*576/8
    unsigned i = blockIdx.x * 256u + threadIdx.x;
    if (i < C1) {
        unsigned e = i * 8u;
        unsigned m = e / 576u, k = e - m * 576u;
        const float* p = (k < 512u) ? x + (size_t)m * 512u + k
                                    : inp + (size_t)m * 64u + (k - 512u);
        f32x4 a = *(const f32x4*)p, b = *(const f32x4*)(p + 4);
        bf16x8 o;
#pragma unroll
        for (int j = 0; j < 4; ++j) { o[j] = (__bf16)a[j]; o[j + 4] = (__bf16)b[j]; }
        *(bf16x8*)&xc[e] = o;
    } else if (i < C1 + C2) {
        unsigned e = (i - C1) * 8u;
        f32x4 a = *(const f32x4*)&Wqkv[e], b = *(const f32x4*)&Wqkv[e + 4];
        bf16x8 o;
#pragma unroll
        for (int j = 0; j < 4; ++j) { o[j] = (__bf16)a[j]; o[j + 4] = (__bf16)b[j]; }
        *(bf16x8*)&wq[e] = o;
    } else {
        unsigned e = (i - C1 - C2) * 8u;
        f32x4 a = *(const f32x4*)&Wo[e], b = *(const f32x4*)&Wo[e + 4];
        bf16x8 o;
#pragma unroll
        for (int j = 0; j < 4; ++j) { o[j] = (__bf16)a[j]; o[j + 4] = (__bf16)b[j]; }
        *(bf16x8*)&wo[e] = o;
    }
}

// ---------------- QKV GEMM (m97 structure): 128x128 tile, BK=32, global_load_lds ----------------
__global__ __launch_bounds__(256) void k_qkv_gemm(
    const __bf16* __restrict__ A, const __bf16* __restrict__ W,
    const float* __restrict__ bias,
    __bf16* __restrict__ q_ws, __bf16* __restrict__ k_ws, __bf16* __restrict__ vt_ws)
{
    const int K = 576;
    __shared__ __align__(16) __bf16 As[128][32];
    __shared__ __align__(16) __bf16 Bs[128][32];
    int m0 = blockIdx.x * 128, n0 = blockIdx.y * 128;
    int t = threadIdx.x, w = t >> 6, l = t & 63;
    int lo = l & 15, hi = l >> 4;
    int wr = w >> 1, wc = w & 1;

    const __bf16* gA = A + (size_t)(m0 + w * 16 + (l >> 2)) * K + (l & 3) * 8;
    const __bf16* gB = W + (size_t)(n0 + w * 16 + (l >> 2)) * K + (l & 3) * 8;
    char* lA = (char*)&As[0][0] + w * 1024;
    char* lB = (char*)&Bs[0][0] + w * 1024;

    f32x4 acc[4][4] = {};
    for (int k0 = 0; k0 < K; k0 += 32) {
        gload_lds16(gA + k0, lA);
        gload_lds16(gA + 64 * K + k0, lA + 4096);
        gload_lds16(gB + k0, lB);
        gload_lds16(gB + 64 * K + k0, lB + 4096);
        __syncthreads();
        bf16x8 af[4], bq[4];
#pragma unroll
        for (int mi = 0; mi < 4; ++mi) af[mi] = *(const bf16x8*)&As[wr * 64 + mi * 16 + lo][hi * 8];
#pragma unroll
        for (int ni = 0; ni < 4; ++ni) bq[ni] = *(const bf16x8*)&Bs[wc * 64 + ni * 16 + lo][hi * 8];
#pragma unroll
        for (int mi = 0; mi < 4; ++mi)
#pragma unroll
            for (int ni = 0; ni < 4; ++ni)
                acc[mi][ni] = MFMA16(af[mi], bq[ni], acc[mi][ni]);
        __syncthreads();
    }

#pragma unroll
    for (int ni = 0; ni < 4; ++ni) {
        int n = n0 + wc * 64 + ni * 16 + lo;
        int h = n / 192, jj = n % 192, part = jj >> 6, d = jj & 63;
        float bn = bias[n];
#pragma unroll
        for (int mi = 0; mi < 4; ++mi)
#pragma unroll
            for (int j = 0; j < 4; ++j) {
                int m = m0 + wr * 64 + mi * 16 + hi * 4 + j;
                float v = acc[mi][ni][j] + bn;
                int b = m >> 10, s = m & 1023;
                size_t bh = (size_t)(b * 8 + h);
                if (part == 0)      q_ws[(bh * 1024 + s) * 64 + d] = (__bf16)(v * 0.125f);
                else if (part == 1) k_ws[(bh * 1024 + s) * 64 + d] = (__bf16)v;
                else                vt_ws[(bh * 64 + d) * 1024 + s] = (__bf16)v;
            }
    }
}

// ---------------- fused attention v11: 2-tile software pipeline (stats/emit overlap) ----------------
// Block handles tiles A=(bh, 2p), B=(bh, 2p+1), 64 rows each. Phases:
//   1: stats(A)            — 16 chunks, no stores
//   2: emit(A) + stats(B)  — 16 chunks, att stores flowing, shared K staging
//   3: emit(B)             — 16 chunks, att stores flowing
__global__ __launch_bounds__(256, 2) void k_attn(
    const __bf16* __restrict__ q_ws, const __bf16* __restrict__ k_ws,
    const __bf16* __restrict__ vt_ws,
    float* __restrict__ att_out, __bf16* __restrict__ values)
{
    __shared__ __align__(16) __bf16 Klds[2][64][76];     // 19,456 B
    __shared__ __align__(16) __bf16 Pl[2][4][16][76];    // 19,456 B -> 38 KB

    int bid = blockIdx.x;                    // grid = 512 (64 bh x 8 tile-pairs)
    int nid = (bid & 7) * 64 + (bid >> 3);   // bijective XCD swizzle (512 % 8 == 0)
    int bh = nid >> 3, pr = nid & 7;
    int t = threadIdx.x, w = t >> 6, l = t & 63;
    int lo = l & 15, hi = l >> 4;
    int q0A = pr * 128 + w * 16;             // tile A rows (wave-owned 16)
    int q0B = q0A + 64;                      // tile B rows

    const __bf16* QgA = q_ws + ((size_t)bh * 1024 + q0A + lo) * 64 + hi * 8;
    const __bf16* QgB = q_ws + ((size_t)bh * 1024 + q0B + lo) * 64 + hi * 8;
    bf16x8 qaA0 = *(const bf16x8*)QgA;
    bf16x8 qaA1 = *(const bf16x8*)(QgA + 32);
    bf16x8 qaB0 = *(const bf16x8*)QgB;
    bf16x8 qaB1 = *(const bf16x8*)(QgB + 32);

    const __bf16* Kb = k_ws + (size_t)bh * 65536;
    int srow = t >> 2, scol = (t & 3) * 16;
    const __bf16* gK = Kb + (size_t)srow * 64 + scol;
    bf16x8 r0, r1;

#define STAGE_LOAD(c)  { const __bf16* p_ = gK + (size_t)(c) * 4096; \
                         r0 = *(const bf16x8*)p_; r1 = *(const bf16x8*)(p_ + 8); }
#define STAGE_WRITE(b) { *(bf16x8*)&Klds[b][srow][scol] = r0; \
                         *(bf16x8*)&Klds[b][srow][scol + 8] = r1; }
#define SCHUNK(b, s, qa0, qa1) _Pragma("unroll") \
                       for (int kk = 0; kk < 4; ++kk) { \
                           bf16x8 kb0 = *(const bf16x8*)&Klds[b][kk * 16 + lo][hi * 8]; \
                           bf16x8 kb1 = *(const bf16x8*)&Klds[b][kk * 16 + lo][hi * 8 + 32]; \
                           f32x4 a_ = {}; \
                           a_ = MFMA16(qa0, kb0, a_); \
                           a_ = MFMA16(qa1, kb1, a_); \
                           s[kk] = a_; \
                       }
#define ONLINE(s, lmx, lsum) _Pragma("unroll") \
                       for (int j = 0; j < 4; ++j) { \
                           float cm = fmaxf(fmaxf(s[0][j], s[1][j]), fmaxf(s[2][j], s[3][j])); \
                           float nm = fmaxf(lmx[j], cm); \
                           float a = __expf(s[0][j] - nm) + __expf(s[1][j] - nm) \
                                   + __expf(s[2][j] - nm) + __expf(s[3][j] - nm); \
                           lsum[j] = lsum[j] * __expf(lmx[j] - nm) + a; \
                           lmx[j] = nm; \
                       }
#define REDUCE(lmx, lsum, gmx, ginv) { \
                       gmx = lmx; \
                       _Pragma("unroll") \
                       for (int off = 1; off < 16; off <<= 1) \
                           _Pragma("unroll") \
                           for (int j = 0; j < 4; ++j) gmx[j] = fmaxf(gmx[j], __shfl_xor(gmx[j], off)); \
                       f32x4 part_; \
                       _Pragma("unroll") \
                       for (int j = 0; j < 4; ++j) part_[j] = lsum[j] * __expf(lmx[j] - gmx[j]); \
                       _Pragma("unroll") \
                       for (int off = 1; off < 16; off <<= 1) \
                           _Pragma("unroll") \
                           for (int j = 0; j < 4; ++j) part_[j] += __shfl_xor(part_[j], off); \
                       _Pragma("unroll") \
                       for (int j = 0; j < 4; ++j) ginv[j] = 1.f / part_[j]; }
#define EMIT(s, gmx, ginv, gatt, pb) _Pragma("unroll") \
                       for (int kk = 0; kk < 4; ++kk) \
                           _Pragma("unroll") \
                           for (int j = 0; j < 4; ++j) { \
                               float p = __expf(s[kk][j] - gmx[j]) * ginv[j]; \
                               gatt[(size_t)(hi * 4 + j) * 1024 + c * 64 + kk * 16 + lo] = p; \
                               Pl[pb][w][hi * 4 + j][kk * 16 + lo] = (__bf16)p; \
                           }
#define PV(cc, oacc)   { int pb_ = (cc) & 1; \
                         const __bf16* vp_ = Vb + (size_t)(cc) * 64; \
                         bf16x8 vb0 = *(const bf16x8*)vp_; \
                         bf16x8 vb1 = *(const bf16x8*)(vp_ + 32); \
                         _Pragma("unroll") \
                         for (int g = 0; g < 4; ++g) { \
                             bf16x8 pa0 = *(const bf16x8*)&Pl[pb_][g][lo][hi * 8]; \
                             bf16x8 pa1 = *(const bf16x8*)&Pl[pb_][g][lo][hi * 8 + 32]; \
                             oacc[g] = MFMA16(pa0, vb0, oacc[g]); \
                             oacc[g] = MFMA16(pa1, vb1, oacc[g]); \
                         } }
#define VSTORE(qt, oacc) _Pragma("unroll") \
                       for (int g = 0; g < 4; ++g) \
                           _Pragma("unroll") \
                           for (int j = 0; j < 4; ++j) \
                               values[((size_t)(bh >> 3) * 1024 + (qt) * 64 + g * 16 + hi * 4 + j) * 512 \
                                      + (bh & 7) * 64 + w * 16 + lo] = (__bf16)oacc[g][j];

    const __bf16* Vb = vt_ws + (size_t)bh * 65536 + (size_t)(w * 16 + lo) * 1024 + hi * 8;
    float* gattA = att_out + ((size_t)bh * 1024 + q0A) * 1024;
    float* gattB = att_out + ((size_t)bh * 1024 + q0B) * 1024;

    f32x4 lmx = { -3.4e38f, -3.4e38f, -3.4e38f, -3.4e38f };
    f32x4 lsum = {};
    f32x4 gmxA, ginvA, gmxB, ginvB;

    // ---- phase 1: stats(A) ----
    STAGE_LOAD(0); STAGE_WRITE(0);
    __syncthreads();
    for (int c = 0; c < 16; ++c) {
        if (c < 15) STAGE_LOAD(c + 1);
        f32x4 s[4];
        SCHUNK(c & 1, s, qaA0, qaA1);
        ONLINE(s, lmx, lsum);
        if (c < 15) STAGE_WRITE((c + 1) & 1);
        __syncthreads();
    }
    REDUCE(lmx, lsum, gmxA, ginvA);

    // ---- phase 2: emit(A) + stats(B); PV(A) lagged ----
    f32x4 oaccA[4] = {};
#pragma unroll
    for (int j = 0; j < 4; ++j) { lmx[j] = -3.4e38f; lsum[j] = 0.f; }
    STAGE_LOAD(0); STAGE_WRITE(0);
    __syncthreads();
    for (int c = 0; c < 16; ++c) {
        if (c < 15) STAGE_LOAD(c + 1);
        {
            f32x4 s[4];
            SCHUNK(c & 1, s, qaA0, qaA1);
            EMIT(s, gmxA, ginvA, gattA, c & 1);
        }
        {
            f32x4 s[4];
            SCHUNK(c & 1, s, qaB0, qaB1);
            ONLINE(s, lmx, lsum);
        }
        if (c > 0) PV(c - 1, oaccA);
        if (c < 15) STAGE_WRITE((c + 1) & 1);
        __syncthreads();
    }
    REDUCE(lmx, lsum, gmxB, ginvB);

    // ---- phase 3: emit(B); PV(B) lagged; finish A ----
    f32x4 oaccB[4] = {};
    STAGE_LOAD(0); STAGE_WRITE(0);
    PV(15, oaccA);            // Pl[1] from phase-2 c=15, untouched until phase-3 c=1
    VSTORE(pr * 2, oaccA);
    __syncthreads();
    for (int c = 0; c < 16; ++c) {
        if (c < 15) STAGE_LOAD(c + 1);
        {
            f32x4 s[4];
            SCHUNK(c & 1, s, qaB0, qaB1);
            EMIT(s, gmxB, ginvB, gattB, c & 1);
        }
        if (c > 0) PV(c - 1, oaccB);
        if (c < 15) STAGE_WRITE((c + 1) & 1);
        __syncthreads();
    }
    PV(15, oaccB);
    VSTORE(pr * 2 + 1, oaccB);

#undef STAGE_LOAD
#undef STAGE_WRITE
#undef SCHUNK
#undef ONLINE
#undef REDUCE
#undef EMIT
#undef PV
#undef VSTORE
}

// ---------------- output GEMM (m97 structure): [8192x512] @ [512x512] + bias ----------------
__global__ __launch_bounds__(256) void k_out_gemm(
    const __bf16* __restrict__ A, const __bf16* __restrict__ W,
    const float* __restrict__ bias, float* __restrict__ out)
{
    const int K = 512;
    __shared__ __align__(16) __bf16 As[128][32];
    __shared__ __align__(16) __bf16 Bs[128][32];
    int m0 = blockIdx.x * 128, n0 = blockIdx.y * 128;
    int t = threadIdx.x, w = t >> 6, l = t & 63;
    int lo = l & 15, hi = l >> 4;
    int wr = w >> 1, wc = w & 1;

    const __bf16* gA = A + (size_t)(m0 + w * 16 + (l >> 2)) * K + (l & 3) * 8;
    const __bf16* gB = W + (size_t)(n0 + w * 16 + (l >> 2)) * K + (l & 3) * 8;
    char* lA = (char*)&As[0][0] + w * 1024;
    char* lB = (char*)&Bs[0][0] + w * 1024;

    f32x4 acc[4][4] = {};
    for (int k0 = 0; k0 < K; k0 += 32) {
        gload_lds16(gA + k0, lA);
        gload_lds16(gA + 64 * K + k0, lA + 4096);
        gload_lds16(gB + k0, lB);
        gload_lds16(gB + 64 * K + k0, lB + 4096);
        __syncthreads();
        bf16x8 af[4], bq[4];
#pragma unroll
        for (int mi = 0; mi < 4; ++mi) af[mi] = *(const bf16x8*)&As[wr * 64 + mi * 16 + lo][hi * 8];
#pragma unroll
        for (int ni = 0; ni < 4; ++ni) bq[ni] = *(const bf16x8*)&Bs[wc * 64 + ni * 16 + lo][hi * 8];
#pragma unroll
        for (int mi = 0; mi < 4; ++mi)
#pragma unroll
            for (int ni = 0; ni < 4; ++ni)
                acc[mi][ni] = MFMA16(af[mi], bq[ni], acc[mi][ni]);
        __syncthreads();
    }

#pragma unroll
    for (int ni = 0; ni < 4; ++ni) {
        int n = n0 + wc * 64 + ni * 16 + lo;
        float bn = bias[n];
#pragma unroll
        for (int mi = 0; mi < 4; ++mi)
#pragma unroll
            for (int j = 0; j < 4; ++j) {
                int m = m0 + wr * 64 + mi * 16 + hi * 4 + j;
                out[(size_t)m * 512 + n] = acc[mi][ni][j] + bn;
            }
    }
}

extern "C" void kernel_launch(void* const* d_in, const int* in_sizes, int n_in,
                              void* d_out, int out_size, void* d_ws, size_t ws_size,
                              hipStream_t stream)
{
    const float* x    = (const float*)d_in[0];
    const float* inp  = (const float*)d_in[1];
    const float* Wqkv = (const float*)d_in[2];
    const float* bqkv = (const float*)d_in[3];
    const float* Wo   = (const float*)d_in[4];
    const float* bo   = (const float*)d_in[5];

    float* out_o   = (float*)d_out;                    // [8,1024,512]
    float* out_att = out_o + (size_t)8 * 1024 * 512;   // [8,8,1024,1024]

    char* ws = (char*)d_ws;
    __bf16* xc    = (__bf16*)(ws + 0);
    __bf16* wq    = (__bf16*)(ws + 9437184);
    __bf16* wo    = (__bf16*)(ws + 11206656);
    __bf16* q_ws  = (__bf16*)(ws + 11730944);
    __bf16* k_ws  = (__bf16*)(ws + 20119552);
    __bf16* vt_ws = (__bf16*)(ws + 28508160);
    __bf16* vals  = (__bf16*)(ws + 36896768);

    k_convert<<<2864, 256, 0, stream>>>(x, inp, Wqkv, Wo, xc, wq, wo);
    k_qkv_gemm<<<dim3(64, 12), 256, 0, stream>>>(xc, wq, bqkv, q_ws, k_ws, vt_ws);
    k_attn<<<512, 256, 0, stream>>>(q_ws, k_ws, vt_ws, out_att, vals);
    k_out_gemm<<<dim3(64, 4), 256, 0, stream>>>(vals, wo, bo, out_o);
}